// Round 11
// baseline (362.240 us; speedup 1.0000x reference)
//
#include <hip/hip_runtime.h>
#include <stdint.h>

#define B_GRAPHS 256
#define NPER     512
#define EPER     4096
#define DDIM     64
#define KKEEP    1024
#define HIDDEN   256
#define CT       8            // hidden columns per tick
#define NTICK    (HIDDEN/CT)  // 32 ticks
#define STR      12           // LDS row stride: 8 cols + 4 pad = 48B, 16B-aligned

// Kernel A: one 1024-thread block per graph, PRODUCER/CONSUMER wave split.
// Waves 0-7 (role 0): thread n computes node n's 8-column A/B projections for
// tick jt and stages them into double-buffered LDS buf[jt&1].
// Waves 8-15 (role 1): thread owns 8 edges and gathers tick jt-1's tile from
// buf[(jt-1)&1]. ONE uniform barrier per tick orders write(jt)/read(jt-1);
// the write-after-read hazard on buf[jt&1] (last read at tick jt-1) is
// protected by that same barrier.
// Why: R10 evidence -- phase-locked waves leave VALU idle during gather and
// LDS idle during projection (VALUBusy 40%, wall 518K cyc vs 131K VALU +
// 166K LDS). Specialized waves put both pipes to work every tick (m114:
// MFMA/VALU/LDS pipes co-schedule across waves). R6-R9: only one workgroup
// is ever resident per CU, so overlap must come from within the block.
// h is re-read per tick in 16-float chunks; asm clobber stops the compiler
// hoisting 64 floats into registers (R1/R3 trap: RA hard-caps 1024-thread
// kernels at 64 arch VGPRs and spills to scratch at ~800MB traffic).
__global__ __launch_bounds__(1024) void scores_kernel(
    const float* __restrict__ h, const float* __restrict__ W1,
    const float* __restrict__ b1, const float* __restrict__ W2,
    const float* __restrict__ b2, const int* __restrict__ edge0,
    const int* __restrict__ edge1, float* __restrict__ sc_out)
{
  __shared__ __align__(16) float At[2][NPER * STR];  // 2 x 24 KB
  __shared__ __align__(16) float Bt[2][NPER * STR];  // 2 x 24 KB
  const int t    = threadIdx.x;
  const int b    = blockIdx.x;
  const int role = __builtin_amdgcn_readfirstlane(t >> 9);  // wave-uniform
  const int n    = t & (NPER - 1);

  // consumer state: 8 edges per consumer thread (coalesced: lanes consecutive)
  int epk[8];
  float eacc[8];
  if (role) {
#pragma unroll
    for (int i = 0; i < 8; ++i) {
      const size_t e = (size_t)b * EPER + n + i * 512;
      epk[i]  = (edge0[e] & (NPER - 1)) | ((edge1[e] & (NPER - 1)) << 16);
      eacc[i] = 0.f;
    }
  }

  const float* __restrict__ hrow = h + ((size_t)b * NPER + n) * DDIM;

  for (int jt = 0; jt <= NTICK; ++jt) {
    if (role == 0) {
      if (jt < NTICK) {                  // produce tile jt
        const int jc = jt * CT;
        asm volatile("" ::: "memory");   // no h-load hoisting across ticks
        float pa[CT], pb[CT];
#pragma unroll
        for (int jj = 0; jj < CT; ++jj) { pa[jj] = b1[jc + jj]; pb[jj] = 0.f; }
#pragma unroll
        for (int dc = 0; dc < 4; ++dc) {
          const float4* hp = (const float4*)(hrow + dc * 16);
          const float4 h0 = hp[0], h1 = hp[1], h2 = hp[2], h3 = hp[3];
          const float hc[16] = {h0.x,h0.y,h0.z,h0.w, h1.x,h1.y,h1.z,h1.w,
                                h2.x,h2.y,h2.z,h2.w, h3.x,h3.y,h3.z,h3.w};
#pragma unroll
          for (int k = 0; k < 16; ++k) {
            const int d = dc * 16 + k;
            const float hv = hc[k];
#pragma unroll
            for (int jj = 0; jj < CT; ++jj)
              pa[jj] = fmaf(hv, W1[d * HIDDEN + jc + jj], pa[jj]);          // s_loads
#pragma unroll
            for (int jj = 0; jj < CT; ++jj)
              pb[jj] = fmaf(hv, W1[(DDIM + d) * HIDDEN + jc + jj], pb[jj]); // s_loads
          }
        }
        const int p = jt & 1;
        float4 s0 = {pa[0], pa[1], pa[2], pa[3]};
        float4 s1 = {pa[4], pa[5], pa[6], pa[7]};
        ((float4*)(At[p] + n * STR))[0] = s0;
        ((float4*)(At[p] + n * STR))[1] = s1;
        float4 u0 = {pb[0], pb[1], pb[2], pb[3]};
        float4 u1 = {pb[4], pb[5], pb[6], pb[7]};
        ((float4*)(Bt[p] + n * STR))[0] = u0;
        ((float4*)(Bt[p] + n * STR))[1] = u1;
      }
    } else {
      if (jt >= 1) {                     // consume tile jt-1
        const int jc = (jt - 1) * CT;
        const int p  = (jt - 1) & 1;
        float w2r[CT];
#pragma unroll
        for (int jj = 0; jj < CT; ++jj) w2r[jj] = W2[jc + jj];  // s_loads
#pragma unroll
        for (int i = 0; i < 8; ++i) {
          const int er = epk[i] & 0xffff;
          const int ec = ((unsigned)epk[i]) >> 16;
          const float4* ar = (const float4*)(At[p] + er * STR);
          const float4* br = (const float4*)(Bt[p] + ec * STR);
          const float4 a0 = ar[0], a1 = ar[1];
          const float4 c0 = br[0], c1 = br[1];
          float q = 0.f;
          q = fmaf(fmaxf(a0.x + c0.x, 0.f), w2r[0], q);
          q = fmaf(fmaxf(a0.y + c0.y, 0.f), w2r[1], q);
          q = fmaf(fmaxf(a0.z + c0.z, 0.f), w2r[2], q);
          q = fmaf(fmaxf(a0.w + c0.w, 0.f), w2r[3], q);
          q = fmaf(fmaxf(a1.x + c1.x, 0.f), w2r[4], q);
          q = fmaf(fmaxf(a1.y + c1.y, 0.f), w2r[5], q);
          q = fmaf(fmaxf(a1.z + c1.z, 0.f), w2r[6], q);
          q = fmaf(fmaxf(a1.w + c1.w, 0.f), w2r[7], q);
          eacc[i] += q;
        }
      }
    }
    __syncthreads();   // one barrier per tick orders produce(jt) / consume(jt-1)
  }

  if (role) {
    const float b2v = b2[0];
#pragma unroll
    for (int i = 0; i < 8; ++i)
      sc_out[(size_t)b * EPER + n + i * 512] = eacc[i] + b2v;
  }
}

// Kernel B: per-graph bitonic sort of (score desc, idx asc) packed u64 keys,
// write causal/spurious edge weights, build node mask from kept edges,
// masked-sum h -> causal_rep. One block per graph.  (R1-verified version.)
__global__ __launch_bounds__(1024) void sort_kernel(
    const float* __restrict__ sc, const int* __restrict__ edge0,
    const int* __restrict__ edge1, const float* __restrict__ h,
    float* __restrict__ out_rep, float* __restrict__ out_cw,
    float* __restrict__ out_sw)
{
  __shared__ unsigned long long keys[EPER];  // 32 KB
  __shared__ int mask[NPER];                 // 2 KB
  __shared__ float red[16 * 64];             // 4 KB
  const int t = threadIdx.x;
  const int b = blockIdx.x;

  if (t < NPER) mask[t] = 0;

  // build keys: ascending u64 order == (score desc, edge idx asc)
#pragma unroll
  for (int i = 0; i < 4; ++i) {
    const int e = t + i * 1024;
    const float s = sc[(size_t)b * EPER + e];
    unsigned u  = __float_as_uint(s);
    unsigned fk = (u & 0x80000000u) ? ~u : (u | 0x80000000u);  // ascending-orderable
    unsigned dk = ~fk;                                          // descending
    keys[e] = ((unsigned long long)dk << 32) | (unsigned)e;
  }

  for (int k = 2; k <= EPER; k <<= 1) {
    for (int j = k >> 1; j > 0; j >>= 1) {
      __syncthreads();
#pragma unroll
      for (int i = 0; i < 4; ++i) {
        const int p = t + i * 1024;
        const int l = p ^ j;
        if (l > p) {
          const unsigned long long a = keys[p], c = keys[l];
          const bool up = ((p & k) == 0);
          if (up ? (a > c) : (a < c)) { keys[p] = c; keys[l] = a; }
        }
      }
    }
  }
  __syncthreads();

  // sorted outputs: positions [0,K) -> causal weights, [K,E) -> -score
#pragma unroll
  for (int i = 0; i < 4; ++i) {
    const int p = t + i * 1024;
    const unsigned long long key = keys[p];
    const unsigned fk = ~(unsigned)(key >> 32);
    const unsigned u  = (fk & 0x80000000u) ? (fk & 0x7fffffffu) : ~fk;  // exact bits back
    const float s = __uint_as_float(u);
    if (p < KKEEP) out_cw[(size_t)b * KKEEP + p] = s;
    else           out_sw[(size_t)b * (EPER - KKEEP) + (p - KKEEP)] = -s;
  }

  // node mask from kept edges (blockDim == KKEEP, so thread t owns position t)
  {
    const int e = (int)(keys[t] & 0xffffffffu);
    const size_t eg = (size_t)b * EPER + e;
    mask[edge0[eg] & (NPER - 1)] = 1;   // same-value LDS races are benign
    mask[edge1[eg] & (NPER - 1)] = 1;
  }
  __syncthreads();

  // masked segment sum: lanes = dims (coalesced h reads), 16 node-groups
  {
    const int d = t & 63, g = t >> 6;
    float s = 0.f;
    for (int nn = g; nn < NPER; nn += 16)
      if (mask[nn]) s += h[((size_t)b * NPER + nn) * DDIM + d];
    red[g * 64 + d] = s;
  }
  __syncthreads();
  if (t < 64) {
    float tot = 0.f;
#pragma unroll
    for (int g = 0; g < 16; ++g) tot += red[g * 64 + t];
    out_rep[(size_t)b * DDIM + t] = tot;
  }
}

extern "C" void kernel_launch(void* const* d_in, const int* in_sizes, int n_in,
                              void* d_out, int out_size, void* d_ws, size_t ws_size,
                              hipStream_t stream) {
  const float* h    = (const float*)d_in[0];
  const float* W1   = (const float*)d_in[1];
  const float* b1   = (const float*)d_in[2];
  const float* W2   = (const float*)d_in[3];
  const float* b2   = (const float*)d_in[4];
  const int*   eidx = (const int*)d_in[5];
  const int* edge0 = eidx;
  const int* edge1 = eidx + (size_t)B_GRAPHS * EPER;

  float* sc = (float*)d_ws;                 // 4 MB scratch for scores

  float* out     = (float*)d_out;
  float* out_rep = out;                                   // 256*64
  float* out_cw  = out + B_GRAPHS * DDIM;                 // 256*1024
  float* out_sw  = out_cw + (size_t)B_GRAPHS * KKEEP;     // 256*3072

  scores_kernel<<<B_GRAPHS, 1024, 0, stream>>>(h, W1, b1, W2, b2, edge0, edge1, sc);
  sort_kernel<<<B_GRAPHS, 1024, 0, stream>>>(sc, edge0, edge1, h, out_rep, out_cw, out_sw);
}